// Round 7
// baseline (74.470 us; speedup 1.0000x reference)
//
#include <hip/hip_runtime.h>

// Problem constants (from reference): NY,NX,NZ,C = 496,432,1,64; N=320000; B=4
#define NY_ 496
#define NX_ 432
#define NZ_ 1
#define C_ 64
#define NVOX_ 320000
#define BATCH_ 4
#define SPATIAL_ (NY_ * NX_ * NZ_)        // 214272 cells per batch (mult of 4)
#define NCELLS_ (BATCH_ * SPATIAL_)       // 857088 total cells

typedef float f32x4 __attribute__((ext_vector_type(4)));
typedef int   i32x4 __attribute__((ext_vector_type(4)));

// K1: vote — last write wins == max voxel index wins (numpy fancy-assign
// semantics). winner[] pre-initialized to -1 via hipMemsetAsync(0xFF).
__global__ void gs_vote(const int* __restrict__ coors, int* __restrict__ winner) {
    int i = blockIdx.x * blockDim.x + threadIdx.x;
    if (i >= NVOX_) return;
    i32x4 czyx = *reinterpret_cast<const i32x4*>(coors + 4 * i); // [b, z, y, x]
    int b = czyx.x, z = czyx.y, y = czyx.z, x = czyx.w;
    int cell = ((b * NY_ + y) * NX_ + x) * NZ_ + z;
    atomicMax(&winner[cell], i);
}

// K2: output-centric fill. Wave-split channel halves: lanes 0-31 do channels
// 0-31, lanes 32-63 do channels 32-63, for the same 32 t-units (4 cells each)
// per block. Unit = 32 KB written (was 64 KB) -> finer scheduling granularity,
// ~half the live VGPRs. Row-major 128 B contiguous loads per winner half-row,
// 4x4 register transpose, NT f32x4 stores (16 B/lane; NT bypasses L2 — R5 A/B
// showed plain stores cost +11 us). Each store instr: 2x512 B contiguous.
__global__ void __launch_bounds__(64)
gs_fill(const float* __restrict__ vf,
        const int* __restrict__ winner,
        float* __restrict__ out) {
    int tid  = threadIdx.x;
    int h    = tid >> 5;                    // channel half: 0 or 1
    int tloc = tid & 31;
    int t    = blockIdx.x * 32 + tloc;      // t in [0, NCELLS_/4)
    int cell0 = t * 4;
    int b  = cell0 / SPATIAL_;
    int sp = cell0 - b * SPATIAL_;

    i32x4 w = *reinterpret_cast<const i32x4*>(winner + cell0);
    float m0 = (w.x >= 0) ? 1.0f : 0.0f;  int i0 = (w.x >= 0) ? w.x : 0;
    float m1 = (w.y >= 0) ? 1.0f : 0.0f;  int i1 = (w.y >= 0) ? w.y : 0;
    float m2 = (w.z >= 0) ? 1.0f : 0.0f;  int i2 = (w.z >= 0) ? w.z : 0;
    float m3 = (w.w >= 0) ? 1.0f : 0.0f;  int i3 = (w.w >= 0) ? w.w : 0;

    int q0 = h * 8;                         // quad offset of this half
    const f32x4* r0 = reinterpret_cast<const f32x4*>(vf + (size_t)i0 * C_) + q0;
    const f32x4* r1 = reinterpret_cast<const f32x4*>(vf + (size_t)i1 * C_) + q0;
    const f32x4* r2 = reinterpret_cast<const f32x4*>(vf + (size_t)i2 * C_) + q0;
    const f32x4* r3 = reinterpret_cast<const f32x4*>(vf + (size_t)i3 * C_) + q0;

    float* outp = out + (size_t)b * C_ * SPATIAL_ + (size_t)(h * 32) * SPATIAL_ + sp;

    f32x4 d0[8], d1[8], d2[8], d3[8];
    // Load phase: row-major, 128 B contiguous per half-row
#pragma unroll
    for (int q = 0; q < 8; ++q) d0[q] = r0[q];
#pragma unroll
    for (int q = 0; q < 8; ++q) d1[q] = r1[q];
#pragma unroll
    for (int q = 0; q < 8; ++q) d2[q] = r2[q];
#pragma unroll
    for (int q = 0; q < 8; ++q) d3[q] = r3[q];
    // Store phase: quad-major 4x4 transpose + NT stores
#pragma unroll
    for (int q = 0; q < 8; ++q) {
        int c = q * 4;
        f32x4 a = d0[q], bb = d1[q], cc = d2[q], dd = d3[q];
        f32x4 o0 = {a.x * m0, bb.x * m1, cc.x * m2, dd.x * m3};
        f32x4 o1 = {a.y * m0, bb.y * m1, cc.y * m2, dd.y * m3};
        f32x4 o2 = {a.z * m0, bb.z * m1, cc.z * m2, dd.z * m3};
        f32x4 o3 = {a.w * m0, bb.w * m1, cc.w * m2, dd.w * m3};
        __builtin_nontemporal_store(o0, reinterpret_cast<f32x4*>(outp + (size_t)(c + 0) * SPATIAL_));
        __builtin_nontemporal_store(o1, reinterpret_cast<f32x4*>(outp + (size_t)(c + 1) * SPATIAL_));
        __builtin_nontemporal_store(o2, reinterpret_cast<f32x4*>(outp + (size_t)(c + 2) * SPATIAL_));
        __builtin_nontemporal_store(o3, reinterpret_cast<f32x4*>(outp + (size_t)(c + 3) * SPATIAL_));
    }
}

extern "C" void kernel_launch(void* const* d_in, const int* in_sizes, int n_in,
                              void* d_out, int out_size, void* d_ws, size_t ws_size,
                              hipStream_t stream) {
    const float* vf    = (const float*)d_in[0];  // (N, C) float32
    const int*   coors = (const int*)d_in[1];    // (N, 4) int32 [b,z,y,x]
    // d_in[2] = batch_size scalar (fixed at 4, baked into constants)
    float* out  = (float*)d_out;                 // (B, C, NY, NX, NZ) float32
    int* winner = (int*)d_ws;                    // NCELLS_ ints = 3.43 MB scratch

    hipMemsetAsync(winner, 0xFF, (size_t)NCELLS_ * sizeof(int), stream); // -1 fill
    gs_vote<<<(NVOX_ + 255) / 256, 256, 0, stream>>>(coors, winner);
    gs_fill<<<NCELLS_ / 4 / 32, 64, 0, stream>>>(vf, winner, out);       // 6696 blocks
}

// Round 8
// 69.713 us; speedup vs baseline: 1.0682x; 1.0682x over previous
//
#include <hip/hip_runtime.h>

// Problem constants (from reference): NY,NX,NZ,C = 496,432,1,64; N=320000; B=4
#define NY_ 496
#define NX_ 432
#define NZ_ 1
#define C_ 64
#define NVOX_ 320000
#define BATCH_ 4
#define SPATIAL_ (NY_ * NX_ * NZ_)        // 214272 cells per batch (mult of 4)
#define NCELLS_ (BATCH_ * SPATIAL_)       // 857088 total cells

typedef float f32x4 __attribute__((ext_vector_type(4)));
typedef int   i32x4 __attribute__((ext_vector_type(4)));

// K1: vote — last write wins == max voxel index wins (numpy fancy-assign
// semantics). winner[] pre-initialized to -1 via hipMemsetAsync(0xFF).
__global__ void gs_vote(const int* __restrict__ coors, int* __restrict__ winner) {
    int i = blockIdx.x * blockDim.x + threadIdx.x;
    if (i >= NVOX_) return;
    i32x4 czyx = *reinterpret_cast<const i32x4*>(coors + 4 * i); // [b, z, y, x]
    int b = czyx.x, z = czyx.y, y = czyx.z, x = czyx.w;
    int cell = ((b * NY_ + y) * NX_ + x) * NZ_ + z;
    atomicMax(&winner[cell], i);
}

// K2: output-centric fill — exact R6 structure (best: 69.8 us).
// One thread per 4 consecutive cells, all 64 channels. 64-thread blocks
// (3348 blocks, ~13/CU). Row-major 128 B contiguous loads per winner row,
// 4x4 register transpose, NT f32x4 stores (16 B/lane, 1 KB contiguous per
// wave-instr; NT bypasses L2 so the 219 MB write stream doesn't evict the
// gathered vf rows — R5 A/B: plain stores +11 us; R7: wave-split halves +4.7 us).
__global__ void __launch_bounds__(64)
gs_fill(const float* __restrict__ vf,
        const int* __restrict__ winner,
        float* __restrict__ out) {
    int t = blockIdx.x * blockDim.x + threadIdx.x;   // NCELLS_/4 threads
    int cell0 = t * 4;
    int b  = cell0 / SPATIAL_;
    int sp = cell0 - b * SPATIAL_;

    i32x4 w = *reinterpret_cast<const i32x4*>(winner + cell0);
    float m0 = (w.x >= 0) ? 1.0f : 0.0f;  int i0 = (w.x >= 0) ? w.x : 0;
    float m1 = (w.y >= 0) ? 1.0f : 0.0f;  int i1 = (w.y >= 0) ? w.y : 0;
    float m2 = (w.z >= 0) ? 1.0f : 0.0f;  int i2 = (w.z >= 0) ? w.z : 0;
    float m3 = (w.w >= 0) ? 1.0f : 0.0f;  int i3 = (w.w >= 0) ? w.w : 0;

    const f32x4* r0 = reinterpret_cast<const f32x4*>(vf + (size_t)i0 * C_);
    const f32x4* r1 = reinterpret_cast<const f32x4*>(vf + (size_t)i1 * C_);
    const f32x4* r2 = reinterpret_cast<const f32x4*>(vf + (size_t)i2 * C_);
    const f32x4* r3 = reinterpret_cast<const f32x4*>(vf + (size_t)i3 * C_);

    float* outp = out + (size_t)b * C_ * SPATIAL_ + sp;

#pragma unroll
    for (int half = 0; half < 2; ++half) {
        int q0 = half * 8;
        f32x4 d0[8], d1[8], d2[8], d3[8];
        // Load phase: row-major, 128 B contiguous per row
#pragma unroll
        for (int q = 0; q < 8; ++q) d0[q] = r0[q0 + q];
#pragma unroll
        for (int q = 0; q < 8; ++q) d1[q] = r1[q0 + q];
#pragma unroll
        for (int q = 0; q < 8; ++q) d2[q] = r2[q0 + q];
#pragma unroll
        for (int q = 0; q < 8; ++q) d3[q] = r3[q0 + q];
        // Store phase: quad-major 4x4 transpose + NT stores
#pragma unroll
        for (int q = 0; q < 8; ++q) {
            int c = (q0 + q) * 4;
            f32x4 a = d0[q], bb = d1[q], cc = d2[q], dd = d3[q];
            f32x4 o0 = {a.x * m0, bb.x * m1, cc.x * m2, dd.x * m3};
            f32x4 o1 = {a.y * m0, bb.y * m1, cc.y * m2, dd.y * m3};
            f32x4 o2 = {a.z * m0, bb.z * m1, cc.z * m2, dd.z * m3};
            f32x4 o3 = {a.w * m0, bb.w * m1, cc.w * m2, dd.w * m3};
            __builtin_nontemporal_store(o0, reinterpret_cast<f32x4*>(outp + (size_t)(c + 0) * SPATIAL_));
            __builtin_nontemporal_store(o1, reinterpret_cast<f32x4*>(outp + (size_t)(c + 1) * SPATIAL_));
            __builtin_nontemporal_store(o2, reinterpret_cast<f32x4*>(outp + (size_t)(c + 2) * SPATIAL_));
            __builtin_nontemporal_store(o3, reinterpret_cast<f32x4*>(outp + (size_t)(c + 3) * SPATIAL_));
        }
    }
}

extern "C" void kernel_launch(void* const* d_in, const int* in_sizes, int n_in,
                              void* d_out, int out_size, void* d_ws, size_t ws_size,
                              hipStream_t stream) {
    const float* vf    = (const float*)d_in[0];  // (N, C) float32
    const int*   coors = (const int*)d_in[1];    // (N, 4) int32 [b,z,y,x]
    // d_in[2] = batch_size scalar (fixed at 4, baked into constants)
    float* out  = (float*)d_out;                 // (B, C, NY, NX, NZ) float32
    int* winner = (int*)d_ws;                    // NCELLS_ ints = 3.43 MB scratch

    hipMemsetAsync(winner, 0xFF, (size_t)NCELLS_ * sizeof(int), stream); // -1 fill
    gs_vote<<<(NVOX_ + 255) / 256, 256, 0, stream>>>(coors, winner);
    gs_fill<<<NCELLS_ / 4 / 64, 64, 0, stream>>>(vf, winner, out);       // 3348 blocks
}